// Round 5
// baseline (254.635 us; speedup 1.0000x reference)
//
#include <hip/hip_runtime.h>
#include <hip/hip_bf16.h>

#define N_NODES  10000
#define N_EDGES  320000
#define N_GRAPHS 64

__device__ __forceinline__ float sigm(float z) { return 1.0f / (1.0f + __expf(-z)); }

// round-to-nearest-even f32 -> bf16 bits
__device__ __forceinline__ unsigned short f2bf(float f) {
    unsigned int u = __float_as_uint(f);
    return (unsigned short)((u + 0x7fffu + ((u >> 16) & 1u)) >> 16);
}
__device__ __forceinline__ float bflo(unsigned int u) { return __uint_as_float(u << 16); }
__device__ __forceinline__ float bfhi(unsigned int u) { return __uint_as_float(u & 0xffff0000u); }

// ---------------- setup: zero deg/g + int-width detection ----------------
// flags[0]: edge_index is int32 (1) vs int64 (0); flags[1]: same for batch
__global__ void setup_k(const unsigned int* __restrict__ ei_raw,
                        const unsigned int* __restrict__ batch_raw,
                        int* __restrict__ flags, int* __restrict__ deg,
                        unsigned int* __restrict__ g) {
    int tid = blockIdx.x * blockDim.x + threadIdx.x;
    int stride = gridDim.x * blockDim.x;
    for (int i = tid; i < N_NODES; i += stride) deg[i] = 0;
    for (int i = tid; i < N_GRAPHS * 256; i += stride) g[i] = 0u;
    if (blockIdx.x == 0) {
        __shared__ int s[2];
        if (threadIdx.x < 2) s[threadIdx.x] = 0;
        __syncthreads();
        int t = threadIdx.x;
        int nz = 0;
        for (int i = 2 * t + 1; i < 2000; i += 512) nz += (ei_raw[i] != 0);
        if (nz) atomicAdd(&s[0], nz);
        nz = 0;
        for (int i = 2 * t + 1; i < 2000; i += 512) nz += (batch_raw[i] != 0);
        if (nz) atomicAdd(&s[1], nz);
        __syncthreads();
        if (threadIdx.x == 0) {
            flags[0] = s[0] > 10 ? 1 : 0;
            flags[1] = s[1] > 10 ? 1 : 0;
        }
    }
}

// normalize ints to int32 + degree histogram (fused)
__global__ void repack_hist_k(const int* __restrict__ ei, const int* __restrict__ batch,
                              const int* __restrict__ flags, int* __restrict__ src,
                              int* __restrict__ dst, int* __restrict__ bat,
                              int* __restrict__ deg) {
    int i = blockIdx.x * blockDim.x + threadIdx.x;
    int i32e = flags[0], i32b = flags[1];
    if (i < N_EDGES) {
        int s = i32e ? ei[i] : ei[2 * i];
        int d = i32e ? ei[N_EDGES + i] : ei[2 * (N_EDGES + i)];
        src[i] = s;
        dst[i] = d;
        atomicAdd(&deg[d], 1);
    }
    if (i < N_NODES) bat[i] = i32b ? batch[i] : batch[2 * i];
}

// single-pass exclusive scan: 1024 threads x 10 elements
__global__ void scan_k(const int* __restrict__ deg, int* __restrict__ offs,
                       int* __restrict__ cursor, int n) {
    __shared__ int sums[1024];
    int t = threadIdx.x;
    int base = t * 10;
    int v[10];
    int run = 0;
    for (int k = 0; k < 10; k++) {
        int i = base + k;
        int d = (i < n) ? deg[i] : 0;
        v[k] = run;
        run += d;
    }
    sums[t] = run;
    __syncthreads();
    for (int dd = 1; dd < 1024; dd <<= 1) {
        int val = (t >= dd) ? sums[t - dd] : 0;
        __syncthreads();
        sums[t] += val;
        __syncthreads();
    }
    int excl = (t == 0) ? 0 : sums[t - 1];
    for (int k = 0; k < 10; k++) {
        int i = base + k;
        if (i < n) { int o = excl + v[k]; offs[i] = o; cursor[i] = o; }
    }
    if (t == 1023) offs[n] = sums[1023];
}

__global__ void scatter_k(const int* __restrict__ src, const int* __restrict__ dst,
                          int* __restrict__ cursor, int* __restrict__ csr, int E) {
    int e = blockIdx.x * blockDim.x + threadIdx.x;
    if (e < E) {
        int pos = atomicAdd(&cursor[dst[e]], 1);
        csr[pos] = src[e];
    }
}

// ---------------- EdgeConv1 node-level linear parts ----------------
// P1[n][c] = x[n]·(W1[0:3]-W1[3:6])[c] + b1[c]  (f32)
// Q1[n][c] = x[n]·W1[3:6][c]                    (bf16)
__global__ void pq1_k(const float* __restrict__ x, const float* __restrict__ W1,
                      const float* __restrict__ b1, float* __restrict__ P1,
                      unsigned short* __restrict__ Q1, int n) {
    __shared__ float xs[96];
    int c = threadIdx.x;  // 0..255
    float k0, k1, k2, bias;
    if (c < 128) {
        k0 = W1[0 * 128 + c] - W1[3 * 128 + c];
        k1 = W1[1 * 128 + c] - W1[4 * 128 + c];
        k2 = W1[2 * 128 + c] - W1[5 * 128 + c];
        bias = b1[c];
    } else {
        int cc = c - 128;
        k0 = W1[3 * 128 + cc];
        k1 = W1[4 * 128 + cc];
        k2 = W1[5 * 128 + cc];
        bias = 0.f;
    }
    int n0 = blockIdx.x * 32;
    int nmax = min(32, n - n0);
    if (threadIdx.x < 96)
        xs[threadIdx.x] = (threadIdx.x < nmax * 3) ? x[n0 * 3 + threadIdx.x] : 0.f;
    __syncthreads();
    for (int t = 0; t < nmax; t++) {
        float v = bias + xs[t * 3 + 0] * k0 + xs[t * 3 + 1] * k1 + xs[t * 3 + 2] * k2;
        if (c < 128) P1[(n0 + t) * 128 + c] = v;
        else         Q1[(n0 + t) * 128 + (c - 128)] = f2bf(v);
    }
}

// one block (64 thr) per node: h1[i][c] = deg>0 ? sigmoid(P1[i][c] + max_e Q1[src_e][c]) : 0
__global__ void econv1_k(const float* __restrict__ P1, const unsigned int* __restrict__ Q1u,
                         const int* __restrict__ offs, const int* __restrict__ csr,
                         float* __restrict__ h1) {
    int i = blockIdx.x;
    int c = threadIdx.x;  // 0..63 -> channels 2c, 2c+1
    int s = offs[i], e = offs[i + 1];
    float2 out = make_float2(0.f, 0.f);
    if (e > s) {
        float z0 = -3.4e38f, z1 = -3.4e38f;
        int k = s;
        for (; k + 3 < e; k += 4) {
            int j0 = csr[k], j1 = csr[k + 1], j2 = csr[k + 2], j3 = csr[k + 3];
            unsigned int u0 = Q1u[j0 * 64 + c];
            unsigned int u1 = Q1u[j1 * 64 + c];
            unsigned int u2 = Q1u[j2 * 64 + c];
            unsigned int u3 = Q1u[j3 * 64 + c];
            z0 = fmaxf(z0, fmaxf(fmaxf(bflo(u0), bflo(u1)), fmaxf(bflo(u2), bflo(u3))));
            z1 = fmaxf(z1, fmaxf(fmaxf(bfhi(u0), bfhi(u1)), fmaxf(bfhi(u2), bfhi(u3))));
        }
        for (; k < e; k++) {
            unsigned int u = Q1u[csr[k] * 64 + c];
            z0 = fmaxf(z0, bflo(u));
            z1 = fmaxf(z1, bfhi(u));
        }
        float2 p = *(const float2*)&P1[i * 128 + 2 * c];
        out.x = sigm(p.x + z0);
        out.y = sigm(p.y + z1);
    }
    *(float2*)&h1[i * 128 + 2 * c] = out;
}

// ---------------- GEMM2: [10000,128] @ Wc[128,512] -> P2 f32 (+b2) | Q2 bf16 ----------
// Wc is formed on the fly from W2: Wc[k][j] = j<256 ? W2[k][j]-W2[128+k][j] : W2[128+k][j-256]
__global__ __launch_bounds__(256) void gemm2_k(const float* __restrict__ h1,
                                               const float* __restrict__ W2,
                                               const float* __restrict__ b2,
                                               float* __restrict__ P2,
                                               unsigned short* __restrict__ Q2, int n) {
    __shared__ float As[32][132];
    __shared__ float Bs[128][64];
    int m0 = blockIdx.x * 32;
    int n0 = blockIdx.y * 64;
    int t = threadIdx.x;

    // stage A: 32x128 floats = 1024 float4, 4 per thread
    for (int it = 0; it < 4; it++) {
        int f4 = t + it * 256;
        int row = f4 >> 5, col = (f4 & 31) << 2;
        float4 v = make_float4(0.f, 0.f, 0.f, 0.f);
        if (m0 + row < n) v = *(const float4*)&h1[(m0 + row) * 128 + col];
        *(float4*)&As[row][col] = v;
    }
    // stage B: compute Wc tile from W2 (branch is block-uniform)
    if (n0 < 256) {
        for (int it = 0; it < 8; it++) {
            int f4 = t + it * 256;
            int row = f4 >> 4, col = (f4 & 15) << 2;
            float4 a = *(const float4*)&W2[row * 256 + n0 + col];
            float4 b = *(const float4*)&W2[(128 + row) * 256 + n0 + col];
            *(float4*)&Bs[row][col] = make_float4(a.x - b.x, a.y - b.y, a.z - b.z, a.w - b.w);
        }
    } else {
        for (int it = 0; it < 8; it++) {
            int f4 = t + it * 256;
            int row = f4 >> 4, col = (f4 & 15) << 2;
            *(float4*)&Bs[row][col] = *(const float4*)&W2[(128 + row) * 256 + (n0 - 256) + col];
        }
    }
    __syncthreads();

    int tr = t >> 4, tc = t & 15;
    float4 acc0 = make_float4(0.f, 0.f, 0.f, 0.f);
    float4 acc1 = make_float4(0.f, 0.f, 0.f, 0.f);
#pragma unroll
    for (int k = 0; k < 128; k += 4) {
        float4 a0 = *(const float4*)&As[tr * 2 + 0][k];
        float4 a1 = *(const float4*)&As[tr * 2 + 1][k];
        float4 b0 = *(const float4*)&Bs[k + 0][tc * 4];
        float4 b1 = *(const float4*)&Bs[k + 1][tc * 4];
        float4 b2v = *(const float4*)&Bs[k + 2][tc * 4];
        float4 b3 = *(const float4*)&Bs[k + 3][tc * 4];
        acc0.x += a0.x * b0.x + a0.y * b1.x + a0.z * b2v.x + a0.w * b3.x;
        acc0.y += a0.x * b0.y + a0.y * b1.y + a0.z * b2v.y + a0.w * b3.y;
        acc0.z += a0.x * b0.z + a0.y * b1.z + a0.z * b2v.z + a0.w * b3.z;
        acc0.w += a0.x * b0.w + a0.y * b1.w + a0.z * b2v.w + a0.w * b3.w;
        acc1.x += a1.x * b0.x + a1.y * b1.x + a1.z * b2v.x + a1.w * b3.x;
        acc1.y += a1.x * b0.y + a1.y * b1.y + a1.z * b2v.y + a1.w * b3.y;
        acc1.z += a1.x * b0.z + a1.y * b1.z + a1.z * b2v.z + a1.w * b3.z;
        acc1.w += a1.x * b0.w + a1.y * b1.w + a1.z * b2v.w + a1.w * b3.w;
    }

    int ncol = n0 + tc * 4;
    if (ncol < 256) {
        float4 bb = *(const float4*)&b2[ncol];
        int m = m0 + tr * 2;
        if (m < n)
            *(float4*)&P2[(size_t)m * 256 + ncol] =
                make_float4(acc0.x + bb.x, acc0.y + bb.y, acc0.z + bb.z, acc0.w + bb.w);
        if (m + 1 < n)
            *(float4*)&P2[(size_t)(m + 1) * 256 + ncol] =
                make_float4(acc1.x + bb.x, acc1.y + bb.y, acc1.z + bb.z, acc1.w + bb.w);
    } else {
        int qcol = ncol - 256;
        int m = m0 + tr * 2;
        if (m < n) {
            ushort4 q;
            q.x = f2bf(acc0.x); q.y = f2bf(acc0.y); q.z = f2bf(acc0.z); q.w = f2bf(acc0.w);
            *(ushort4*)&Q2[(size_t)m * 256 + qcol] = q;
        }
        if (m + 1 < n) {
            ushort4 q;
            q.x = f2bf(acc1.x); q.y = f2bf(acc1.y); q.z = f2bf(acc1.z); q.w = f2bf(acc1.w);
            *(ushort4*)&Q2[(size_t)(m + 1) * 256 + qcol] = q;
        }
    }
}

// ---------------- EdgeConv2 + fused graph max-pool ----------------
// one block (64 thr = 1 wave) per node, channels {4c..4c+3} per thread, uint2 gathers
__global__ void econv2_k(const float* __restrict__ P2, const uint2* __restrict__ Q2v,
                         const int* __restrict__ offs, const int* __restrict__ csr,
                         const int* __restrict__ bat, float* __restrict__ g) {
    int i = blockIdx.x;
    int s = offs[i], e = offs[i + 1];
    if (s == e) return;  // empty row -> h2 = 0, contributes nothing (g init 0)
    int c = threadIdx.x;  // 0..63
    float z0 = -3.4e38f, z1 = -3.4e38f, z2 = -3.4e38f, z3 = -3.4e38f;
    int k = s;
    for (; k + 3 < e; k += 4) {
        int j0 = csr[k], j1 = csr[k + 1], j2 = csr[k + 2], j3 = csr[k + 3];
        uint2 u0 = Q2v[(size_t)j0 * 64 + c];
        uint2 u1 = Q2v[(size_t)j1 * 64 + c];
        uint2 u2 = Q2v[(size_t)j2 * 64 + c];
        uint2 u3 = Q2v[(size_t)j3 * 64 + c];
        z0 = fmaxf(z0, fmaxf(fmaxf(bflo(u0.x), bflo(u1.x)), fmaxf(bflo(u2.x), bflo(u3.x))));
        z1 = fmaxf(z1, fmaxf(fmaxf(bfhi(u0.x), bfhi(u1.x)), fmaxf(bfhi(u2.x), bfhi(u3.x))));
        z2 = fmaxf(z2, fmaxf(fmaxf(bflo(u0.y), bflo(u1.y)), fmaxf(bflo(u2.y), bflo(u3.y))));
        z3 = fmaxf(z3, fmaxf(fmaxf(bfhi(u0.y), bfhi(u1.y)), fmaxf(bfhi(u2.y), bfhi(u3.y))));
    }
    for (; k < e; k++) {
        uint2 u = Q2v[(size_t)csr[k] * 64 + c];
        z0 = fmaxf(z0, bflo(u.x));
        z1 = fmaxf(z1, bfhi(u.x));
        z2 = fmaxf(z2, bflo(u.y));
        z3 = fmaxf(z3, bfhi(u.y));
    }
    float4 p = *(const float4*)&P2[(size_t)i * 256 + 4 * c];
    float h0 = sigm(p.x + z0);  // > 0 always
    float h1 = sigm(p.y + z1);
    float h2 = sigm(p.z + z2);
    float h3 = sigm(p.w + z3);
    int gb = bat[i] * 256 + 4 * c;
    atomicMax((unsigned int*)&g[gb + 0], __float_as_uint(h0));
    atomicMax((unsigned int*)&g[gb + 1], __float_as_uint(h1));
    atomicMax((unsigned int*)&g[gb + 2], __float_as_uint(h2));
    atomicMax((unsigned int*)&g[gb + 3], __float_as_uint(h3));
}

// ---------------- head: out = sigmoid(g@W3+b3)@W4+b4, f32 out ----------------
__global__ void final_k(const float* __restrict__ g, const float* __restrict__ W3,
                        const float* __restrict__ b3, const float* __restrict__ W4,
                        const float* __restrict__ b4, float* __restrict__ out) {
    __shared__ float gs[256];
    __shared__ float ss[128];
    int b = blockIdx.x, t = threadIdx.x;  // 128 threads
    gs[t] = g[b * 256 + t];
    gs[t + 128] = g[b * 256 + 128 + t];
    __syncthreads();
    float acc = b3[t];
#pragma unroll 8
    for (int k = 0; k < 256; k++) acc += gs[k] * W3[k * 128 + t];
    ss[t] = sigm(acc);
    __syncthreads();
    if (t < 10) {
        float o = b4[t];
#pragma unroll 8
        for (int k = 0; k < 128; k++) o += ss[k] * W4[k * 10 + t];
        out[b * 10 + t] = o;
    }
}

extern "C" void kernel_launch(void* const* d_in, const int* in_sizes, int n_in,
                              void* d_out, int out_size, void* d_ws, size_t ws_size,
                              hipStream_t stream) {
    const float* x  = (const float*)d_in[0];
    const void*  ei_raw = d_in[1];
    const void*  b_raw  = d_in[2];
    const float* W1 = (const float*)d_in[3];
    const float* b1 = (const float*)d_in[4];
    const float* W2 = (const float*)d_in[5];
    const float* b2 = (const float*)d_in[6];
    const float* W3 = (const float*)d_in[7];
    const float* b3 = (const float*)d_in[8];
    const float* W4 = (const float*)d_in[9];
    const float* b4 = (const float*)d_in[10];

    char* ws = (char*)d_ws;
    size_t off = 0;
    auto alloc = [&](size_t bytes) {
        void* p = ws + off;
        off += (bytes + 255) & ~(size_t)255;
        return p;
    };
    int*            flags  = (int*)alloc(16);
    int*            src    = (int*)alloc(N_EDGES * 4);
    int*            dst    = (int*)alloc(N_EDGES * 4);
    int*            bat    = (int*)alloc(N_NODES * 4);
    int*            deg    = (int*)alloc(N_NODES * 4);
    int*            offs   = (int*)alloc((N_NODES + 1) * 4);
    int*            cursor = (int*)alloc(N_NODES * 4);
    int*            csr    = (int*)alloc(N_EDGES * 4);
    float*          P1     = (float*)alloc((size_t)N_NODES * 128 * 4);
    unsigned short* Q1     = (unsigned short*)alloc((size_t)N_NODES * 128 * 2);
    float*          h1     = (float*)alloc((size_t)N_NODES * 128 * 4);
    float*          P2     = (float*)alloc((size_t)N_NODES * 256 * 4);
    unsigned short* Q2     = (unsigned short*)alloc((size_t)N_NODES * 256 * 2);
    float*          g      = (float*)alloc(N_GRAPHS * 256 * 4);

    setup_k<<<64, 256, 0, stream>>>((const unsigned int*)ei_raw, (const unsigned int*)b_raw,
                                    flags, deg, (unsigned int*)g);
    repack_hist_k<<<(N_EDGES + 255) / 256, 256, 0, stream>>>((const int*)ei_raw, (const int*)b_raw,
                                                             flags, src, dst, bat, deg);
    scan_k<<<1, 1024, 0, stream>>>(deg, offs, cursor, N_NODES);
    scatter_k<<<(N_EDGES + 255) / 256, 256, 0, stream>>>(src, dst, cursor, csr, N_EDGES);

    pq1_k<<<(N_NODES + 31) / 32, 256, 0, stream>>>(x, W1, b1, P1, Q1, N_NODES);
    econv1_k<<<N_NODES, 64, 0, stream>>>(P1, (const unsigned int*)Q1, offs, csr, h1);

    gemm2_k<<<dim3((N_NODES + 31) / 32, 8), 256, 0, stream>>>(h1, W2, b2, P2, Q2, N_NODES);

    econv2_k<<<N_NODES, 64, 0, stream>>>(P2, (const uint2*)Q2, offs, csr, bat, g);
    final_k<<<N_GRAPHS, 128, 0, stream>>>(g, W3, b3, W4, b4, (float*)d_out);
}

// Round 6
// 237.352 us; speedup vs baseline: 1.0728x; 1.0728x over previous
//
#include <hip/hip_runtime.h>
#include <hip/hip_bf16.h>

#define N_NODES  10000
#define N_EDGES  320000
#define N_GRAPHS 64

__device__ __forceinline__ float sigm(float z) { return 1.0f / (1.0f + __expf(-z)); }

// round-to-nearest-even f32 -> bf16 bits
__device__ __forceinline__ unsigned short f2bf(float f) {
    unsigned int u = __float_as_uint(f);
    return (unsigned short)((u + 0x7fffu + ((u >> 16) & 1u)) >> 16);
}
__device__ __forceinline__ float bflo(unsigned int u) { return __uint_as_float(u << 16); }
__device__ __forceinline__ float bfhi(unsigned int u) { return __uint_as_float(u & 0xffff0000u); }

// ---------------- setup: zero deg/g + int-width detection ----------------
__global__ void setup_k(const unsigned int* __restrict__ ei_raw,
                        const unsigned int* __restrict__ batch_raw,
                        int* __restrict__ flags, int* __restrict__ deg,
                        unsigned int* __restrict__ g) {
    int tid = blockIdx.x * blockDim.x + threadIdx.x;
    int stride = gridDim.x * blockDim.x;
    for (int i = tid; i < N_NODES; i += stride) deg[i] = 0;
    for (int i = tid; i < N_GRAPHS * 256; i += stride) g[i] = 0u;
    if (blockIdx.x == 0) {
        __shared__ int s[2];
        if (threadIdx.x < 2) s[threadIdx.x] = 0;
        __syncthreads();
        int t = threadIdx.x;
        int nz = 0;
        for (int i = 2 * t + 1; i < 2000; i += 512) nz += (ei_raw[i] != 0);
        if (nz) atomicAdd(&s[0], nz);
        nz = 0;
        for (int i = 2 * t + 1; i < 2000; i += 512) nz += (batch_raw[i] != 0);
        if (nz) atomicAdd(&s[1], nz);
        __syncthreads();
        if (threadIdx.x == 0) {
            flags[0] = s[0] > 10 ? 1 : 0;
            flags[1] = s[1] > 10 ? 1 : 0;
        }
    }
}

// normalize ints to int32 + degree histogram (fused)
__global__ void repack_hist_k(const int* __restrict__ ei, const int* __restrict__ batch,
                              const int* __restrict__ flags, int* __restrict__ src,
                              int* __restrict__ dst, int* __restrict__ bat,
                              int* __restrict__ deg) {
    int i = blockIdx.x * blockDim.x + threadIdx.x;
    int i32e = flags[0], i32b = flags[1];
    if (i < N_EDGES) {
        int s = i32e ? ei[i] : ei[2 * i];
        int d = i32e ? ei[N_EDGES + i] : ei[2 * (N_EDGES + i)];
        src[i] = s;
        dst[i] = d;
        atomicAdd(&deg[d], 1);
    }
    if (i < N_NODES) bat[i] = i32b ? batch[i] : batch[2 * i];
}

// single-pass exclusive scan: 1024 threads x 10 elements
__global__ void scan_k(const int* __restrict__ deg, int* __restrict__ offs,
                       int* __restrict__ cursor, int n) {
    __shared__ int sums[1024];
    int t = threadIdx.x;
    int base = t * 10;
    int v[10];
    int run = 0;
    for (int k = 0; k < 10; k++) {
        int i = base + k;
        int d = (i < n) ? deg[i] : 0;
        v[k] = run;
        run += d;
    }
    sums[t] = run;
    __syncthreads();
    for (int dd = 1; dd < 1024; dd <<= 1) {
        int val = (t >= dd) ? sums[t - dd] : 0;
        __syncthreads();
        sums[t] += val;
        __syncthreads();
    }
    int excl = (t == 0) ? 0 : sums[t - 1];
    for (int k = 0; k < 10; k++) {
        int i = base + k;
        if (i < n) { int o = excl + v[k]; offs[i] = o; cursor[i] = o; }
    }
    if (t == 1023) offs[n] = sums[1023];
}

__global__ void scatter_k(const int* __restrict__ src, const int* __restrict__ dst,
                          int* __restrict__ cursor, int* __restrict__ csr, int E) {
    int e = blockIdx.x * blockDim.x + threadIdx.x;
    if (e < E) {
        int pos = atomicAdd(&cursor[dst[e]], 1);
        csr[pos] = src[e];
    }
}

// ---------------- EdgeConv1 node-level linear parts ----------------
// P1[n][c] = x[n]·(W1[0:3]-W1[3:6])[c] + b1[c]  (f32)
// Q1[n][c] = x[n]·W1[3:6][c]                    (bf16)
__global__ void pq1_k(const float* __restrict__ x, const float* __restrict__ W1,
                      const float* __restrict__ b1, float* __restrict__ P1,
                      unsigned short* __restrict__ Q1, int n) {
    __shared__ float xs[96];
    int c = threadIdx.x;  // 0..255
    float k0, k1, k2, bias;
    if (c < 128) {
        k0 = W1[0 * 128 + c] - W1[3 * 128 + c];
        k1 = W1[1 * 128 + c] - W1[4 * 128 + c];
        k2 = W1[2 * 128 + c] - W1[5 * 128 + c];
        bias = b1[c];
    } else {
        int cc = c - 128;
        k0 = W1[3 * 128 + cc];
        k1 = W1[4 * 128 + cc];
        k2 = W1[5 * 128 + cc];
        bias = 0.f;
    }
    int n0 = blockIdx.x * 32;
    int nmax = min(32, n - n0);
    if (threadIdx.x < 96)
        xs[threadIdx.x] = (threadIdx.x < nmax * 3) ? x[n0 * 3 + threadIdx.x] : 0.f;
    __syncthreads();
    for (int t = 0; t < nmax; t++) {
        float v = bias + xs[t * 3 + 0] * k0 + xs[t * 3 + 1] * k1 + xs[t * 3 + 2] * k2;
        if (c < 128) P1[(n0 + t) * 128 + c] = v;
        else         Q1[(n0 + t) * 128 + (c - 128)] = f2bf(v);
    }
}

// ---------------- EdgeConv1: 256 thr = 4 waves per node, edge-chunked + LDS combine ----
// wave w handles edge chunk [s + len*w/4, s + len*(w+1)/4); lane covers ch {2l, 2l+1}
__global__ __launch_bounds__(256) void econv1_k(const float* __restrict__ P1,
                                                const unsigned int* __restrict__ Q1u,
                                                const int* __restrict__ offs,
                                                const int* __restrict__ csr,
                                                float* __restrict__ h1) {
    __shared__ float zs[4][128];
    int i = blockIdx.x;
    int s = offs[i], e = offs[i + 1];
    int t = threadIdx.x;
    int len = e - s;
    if (len == 0) {
        if (t < 128) h1[i * 128 + t] = 0.f;
        return;
    }
    int wave = t >> 6, lane = t & 63;
    int a = s + (len * wave) / 4;
    int b = s + (len * (wave + 1)) / 4;
    float z0 = -3.4e38f, z1 = -3.4e38f;
    int k = a;
    for (; k + 3 < b; k += 4) {
        int j0 = csr[k], j1 = csr[k + 1], j2 = csr[k + 2], j3 = csr[k + 3];
        unsigned int u0 = Q1u[j0 * 64 + lane];
        unsigned int u1 = Q1u[j1 * 64 + lane];
        unsigned int u2 = Q1u[j2 * 64 + lane];
        unsigned int u3 = Q1u[j3 * 64 + lane];
        z0 = fmaxf(z0, fmaxf(fmaxf(bflo(u0), bflo(u1)), fmaxf(bflo(u2), bflo(u3))));
        z1 = fmaxf(z1, fmaxf(fmaxf(bfhi(u0), bfhi(u1)), fmaxf(bfhi(u2), bfhi(u3))));
    }
    for (; k < b; k++) {
        unsigned int u = Q1u[csr[k] * 64 + lane];
        z0 = fmaxf(z0, bflo(u));
        z1 = fmaxf(z1, bfhi(u));
    }
    *(float2*)&zs[wave][2 * lane] = make_float2(z0, z1);
    __syncthreads();
    if (t < 128) {
        float z = fmaxf(fmaxf(zs[0][t], zs[1][t]), fmaxf(zs[2][t], zs[3][t]));
        h1[i * 128 + t] = sigm(P1[i * 128 + t] + z);
    }
}

// ---------------- GEMM2: [10000,128] @ Wc[128,512] -> P2 f32 (+b2) | Q2 bf16 ----------
// Wc formed on the fly: Wc[k][j] = j<256 ? W2[k][j]-W2[128+k][j] : W2[128+k][j-256]
__global__ __launch_bounds__(256) void gemm2_k(const float* __restrict__ h1,
                                               const float* __restrict__ W2,
                                               const float* __restrict__ b2,
                                               float* __restrict__ P2,
                                               unsigned short* __restrict__ Q2, int n) {
    __shared__ float As[32][132];
    __shared__ float Bs[128][64];
    int m0 = blockIdx.x * 32;
    int n0 = blockIdx.y * 64;
    int t = threadIdx.x;

    for (int it = 0; it < 4; it++) {
        int f4 = t + it * 256;
        int row = f4 >> 5, col = (f4 & 31) << 2;
        float4 v = make_float4(0.f, 0.f, 0.f, 0.f);
        if (m0 + row < n) v = *(const float4*)&h1[(m0 + row) * 128 + col];
        *(float4*)&As[row][col] = v;
    }
    if (n0 < 256) {
        for (int it = 0; it < 8; it++) {
            int f4 = t + it * 256;
            int row = f4 >> 4, col = (f4 & 15) << 2;
            float4 a = *(const float4*)&W2[row * 256 + n0 + col];
            float4 b = *(const float4*)&W2[(128 + row) * 256 + n0 + col];
            *(float4*)&Bs[row][col] = make_float4(a.x - b.x, a.y - b.y, a.z - b.z, a.w - b.w);
        }
    } else {
        for (int it = 0; it < 8; it++) {
            int f4 = t + it * 256;
            int row = f4 >> 4, col = (f4 & 15) << 2;
            *(float4*)&Bs[row][col] = *(const float4*)&W2[(128 + row) * 256 + (n0 - 256) + col];
        }
    }
    __syncthreads();

    int tr = t >> 4, tc = t & 15;
    float4 acc0 = make_float4(0.f, 0.f, 0.f, 0.f);
    float4 acc1 = make_float4(0.f, 0.f, 0.f, 0.f);
#pragma unroll
    for (int k = 0; k < 128; k += 4) {
        float4 a0 = *(const float4*)&As[tr * 2 + 0][k];
        float4 a1 = *(const float4*)&As[tr * 2 + 1][k];
        float4 b0 = *(const float4*)&Bs[k + 0][tc * 4];
        float4 b1 = *(const float4*)&Bs[k + 1][tc * 4];
        float4 b2v = *(const float4*)&Bs[k + 2][tc * 4];
        float4 b3 = *(const float4*)&Bs[k + 3][tc * 4];
        acc0.x += a0.x * b0.x + a0.y * b1.x + a0.z * b2v.x + a0.w * b3.x;
        acc0.y += a0.x * b0.y + a0.y * b1.y + a0.z * b2v.y + a0.w * b3.y;
        acc0.z += a0.x * b0.z + a0.y * b1.z + a0.z * b2v.z + a0.w * b3.z;
        acc0.w += a0.x * b0.w + a0.y * b1.w + a0.z * b2v.w + a0.w * b3.w;
        acc1.x += a1.x * b0.x + a1.y * b1.x + a1.z * b2v.x + a1.w * b3.x;
        acc1.y += a1.x * b0.y + a1.y * b1.y + a1.z * b2v.y + a1.w * b3.y;
        acc1.z += a1.x * b0.z + a1.y * b1.z + a1.z * b2v.z + a1.w * b3.z;
        acc1.w += a1.x * b0.w + a1.y * b1.w + a1.z * b2v.w + a1.w * b3.w;
    }

    int ncol = n0 + tc * 4;
    if (ncol < 256) {
        float4 bb = *(const float4*)&b2[ncol];
        int m = m0 + tr * 2;
        if (m < n)
            *(float4*)&P2[(size_t)m * 256 + ncol] =
                make_float4(acc0.x + bb.x, acc0.y + bb.y, acc0.z + bb.z, acc0.w + bb.w);
        if (m + 1 < n)
            *(float4*)&P2[(size_t)(m + 1) * 256 + ncol] =
                make_float4(acc1.x + bb.x, acc1.y + bb.y, acc1.z + bb.z, acc1.w + bb.w);
    } else {
        int qcol = ncol - 256;
        int m = m0 + tr * 2;
        if (m < n) {
            ushort4 q;
            q.x = f2bf(acc0.x); q.y = f2bf(acc0.y); q.z = f2bf(acc0.z); q.w = f2bf(acc0.w);
            *(ushort4*)&Q2[(size_t)m * 256 + qcol] = q;
        }
        if (m + 1 < n) {
            ushort4 q;
            q.x = f2bf(acc1.x); q.y = f2bf(acc1.y); q.z = f2bf(acc1.z); q.w = f2bf(acc1.w);
            *(ushort4*)&Q2[(size_t)(m + 1) * 256 + qcol] = q;
        }
    }
}

// ---------------- EdgeConv2 + graph pool: 256 thr = 4 waves per node ----------------
// wave w: edge chunk; lane covers ch {4l..4l+3} via uint2; LDS combine; 1 atomic set/node
__global__ __launch_bounds__(256) void econv2_k(const float* __restrict__ P2,
                                                const uint2* __restrict__ Q2v,
                                                const int* __restrict__ offs,
                                                const int* __restrict__ csr,
                                                const int* __restrict__ bat,
                                                float* __restrict__ g) {
    __shared__ float zs[4][256];
    int i = blockIdx.x;
    int s = offs[i], e = offs[i + 1];
    if (s == e) return;  // empty row -> h2 = 0, contributes nothing (g init 0)
    int t = threadIdx.x;
    int wave = t >> 6, lane = t & 63;
    int len = e - s;
    int a = s + (len * wave) / 4;
    int b = s + (len * (wave + 1)) / 4;
    float z0 = -3.4e38f, z1 = -3.4e38f, z2 = -3.4e38f, z3 = -3.4e38f;
    int k = a;
    for (; k + 3 < b; k += 4) {
        int j0 = csr[k], j1 = csr[k + 1], j2 = csr[k + 2], j3 = csr[k + 3];
        uint2 u0 = Q2v[(size_t)j0 * 64 + lane];
        uint2 u1 = Q2v[(size_t)j1 * 64 + lane];
        uint2 u2 = Q2v[(size_t)j2 * 64 + lane];
        uint2 u3 = Q2v[(size_t)j3 * 64 + lane];
        z0 = fmaxf(z0, fmaxf(fmaxf(bflo(u0.x), bflo(u1.x)), fmaxf(bflo(u2.x), bflo(u3.x))));
        z1 = fmaxf(z1, fmaxf(fmaxf(bfhi(u0.x), bfhi(u1.x)), fmaxf(bfhi(u2.x), bfhi(u3.x))));
        z2 = fmaxf(z2, fmaxf(fmaxf(bflo(u0.y), bflo(u1.y)), fmaxf(bflo(u2.y), bflo(u3.y))));
        z3 = fmaxf(z3, fmaxf(fmaxf(bfhi(u0.y), bfhi(u1.y)), fmaxf(bfhi(u2.y), bfhi(u3.y))));
    }
    for (; k < b; k++) {
        uint2 u = Q2v[(size_t)csr[k] * 64 + lane];
        z0 = fmaxf(z0, bflo(u.x));
        z1 = fmaxf(z1, bfhi(u.x));
        z2 = fmaxf(z2, bflo(u.y));
        z3 = fmaxf(z3, bfhi(u.y));
    }
    *(float4*)&zs[wave][4 * lane] = make_float4(z0, z1, z2, z3);
    __syncthreads();
    float z = fmaxf(fmaxf(zs[0][t], zs[1][t]), fmaxf(zs[2][t], zs[3][t]));
    float h = sigm(P2[(size_t)i * 256 + t] + z);  // > 0 always
    atomicMax((unsigned int*)&g[bat[i] * 256 + t], __float_as_uint(h));
}

// ---------------- head: out = sigmoid(g@W3+b3)@W4+b4, f32 out ----------------
__global__ void final_k(const float* __restrict__ g, const float* __restrict__ W3,
                        const float* __restrict__ b3, const float* __restrict__ W4,
                        const float* __restrict__ b4, float* __restrict__ out) {
    __shared__ float gs[256];
    __shared__ float ss[128];
    int b = blockIdx.x, t = threadIdx.x;  // 128 threads
    gs[t] = g[b * 256 + t];
    gs[t + 128] = g[b * 256 + 128 + t];
    __syncthreads();
    float acc = b3[t];
#pragma unroll 8
    for (int k = 0; k < 256; k++) acc += gs[k] * W3[k * 128 + t];
    ss[t] = sigm(acc);
    __syncthreads();
    if (t < 10) {
        float o = b4[t];
#pragma unroll 8
        for (int k = 0; k < 128; k++) o += ss[k] * W4[k * 10 + t];
        out[b * 10 + t] = o;
    }
}

extern "C" void kernel_launch(void* const* d_in, const int* in_sizes, int n_in,
                              void* d_out, int out_size, void* d_ws, size_t ws_size,
                              hipStream_t stream) {
    const float* x  = (const float*)d_in[0];
    const void*  ei_raw = d_in[1];
    const void*  b_raw  = d_in[2];
    const float* W1 = (const float*)d_in[3];
    const float* b1 = (const float*)d_in[4];
    const float* W2 = (const float*)d_in[5];
    const float* b2 = (const float*)d_in[6];
    const float* W3 = (const float*)d_in[7];
    const float* b3 = (const float*)d_in[8];
    const float* W4 = (const float*)d_in[9];
    const float* b4 = (const float*)d_in[10];

    char* ws = (char*)d_ws;
    size_t off = 0;
    auto alloc = [&](size_t bytes) {
        void* p = ws + off;
        off += (bytes + 255) & ~(size_t)255;
        return p;
    };
    int*            flags  = (int*)alloc(16);
    int*            src    = (int*)alloc(N_EDGES * 4);
    int*            dst    = (int*)alloc(N_EDGES * 4);
    int*            bat    = (int*)alloc(N_NODES * 4);
    int*            deg    = (int*)alloc(N_NODES * 4);
    int*            offs   = (int*)alloc((N_NODES + 1) * 4);
    int*            cursor = (int*)alloc(N_NODES * 4);
    int*            csr    = (int*)alloc(N_EDGES * 4);
    float*          P1     = (float*)alloc((size_t)N_NODES * 128 * 4);
    unsigned short* Q1     = (unsigned short*)alloc((size_t)N_NODES * 128 * 2);
    float*          h1     = (float*)alloc((size_t)N_NODES * 128 * 4);
    float*          P2     = (float*)alloc((size_t)N_NODES * 256 * 4);
    unsigned short* Q2     = (unsigned short*)alloc((size_t)N_NODES * 256 * 2);
    float*          g      = (float*)alloc(N_GRAPHS * 256 * 4);

    setup_k<<<64, 256, 0, stream>>>((const unsigned int*)ei_raw, (const unsigned int*)b_raw,
                                    flags, deg, (unsigned int*)g);
    repack_hist_k<<<(N_EDGES + 255) / 256, 256, 0, stream>>>((const int*)ei_raw, (const int*)b_raw,
                                                             flags, src, dst, bat, deg);
    scan_k<<<1, 1024, 0, stream>>>(deg, offs, cursor, N_NODES);
    scatter_k<<<(N_EDGES + 255) / 256, 256, 0, stream>>>(src, dst, cursor, csr, N_EDGES);

    pq1_k<<<(N_NODES + 31) / 32, 256, 0, stream>>>(x, W1, b1, P1, Q1, N_NODES);
    econv1_k<<<N_NODES, 256, 0, stream>>>(P1, (const unsigned int*)Q1, offs, csr, h1);

    gemm2_k<<<dim3((N_NODES + 31) / 32, 8), 256, 0, stream>>>(h1, W2, b2, P2, Q2, N_NODES);

    econv2_k<<<N_NODES, 256, 0, stream>>>(P2, (const uint2*)Q2, offs, csr, bat, g);
    final_k<<<N_GRAPHS, 128, 0, stream>>>(g, W3, b3, W4, b4, (float*)d_out);
}